// Round 16
// baseline (164.520 us; speedup 1.0000x reference)
//
#include <hip/hip_runtime.h>
#include <math.h>

#define ALPHA 0.2f

typedef __attribute__((ext_vector_type(8))) short bf16x8;
typedef __attribute__((ext_vector_type(4))) float f32x4;

static __device__ __forceinline__ float lrelu(float v) {
    return fmaxf(v, ALPHA * v);
}
// fp32 -> bf16 RTNE (software; low-volume paths only)
static __device__ __forceinline__ uint16_t f2b(float f) {
    union { float f; uint32_t u; } c; c.f = f;
    const uint32_t u = c.u + 0x7FFFu + ((c.u >> 16) & 1u);
    return (uint16_t)(u >> 16);
}
// HW packed cvt: low16 = bf16(lo), high16 = bf16(hi), RTNE
static __device__ __forceinline__ uint32_t cvt2(float lo, float hi) {
    uint32_t r;
    asm("v_cvt_pk_bf16_f32 %0, %1, %2" : "=v"(r) : "v"(lo), "v"(hi));
    return r;
}

// ---------------- precompute (unchanged, proven) ---------------------------
__global__ __launch_bounds__(256) void precompute(
    const float* __restrict__ x, const float* __restrict__ w0,
    const float* __restrict__ b0, const float* __restrict__ w1,
    const float* __restrict__ w2, const float* __restrict__ f0,
    const float* __restrict__ f1,
    float* __restrict__ base0T, float* __restrict__ Gp,
    float* __restrict__ xyt, float* __restrict__ wd0,
    uint16_t* __restrict__ wb1, uint16_t* __restrict__ wb2,
    uint16_t* __restrict__ wfn0, uint16_t* __restrict__ wfn1,
    float* __restrict__ hin)
{
    const int blk = blockIdx.x, t = threadIdx.x;
    if (blk >= 256) {
        const int t0 = (blk - 256) * 256 + t;  // 0..7167
        for (int i = t0; i < 160 * 96;  i += 7168) wb1[i]  = f2b(w1[i]);
        for (int i = t0; i < 192 * 160; i += 7168) wb2[i]  = f2b(w2[i]);
        for (int i = t0; i < 256 * 224; i += 7168) wfn0[i] = f2b(f0[i]);
        for (int i = t0; i < 256 * 256; i += 7168) wfn1[i] = f2b(f1[i]);
        if (t0 < 96) wd0[t0] = w0[t0 * 65 + 64];
        return;
    }
    __shared__ float W0s[96 * 65];
    __shared__ float xs[25 * 32];
    const int r0 = blk * 25;
    for (int i = t; i < 96 * 65; i += 256) W0s[i] = w0[i];
    for (int i = t; i < 800; i += 256) xs[i] = x[r0 * 32 + i];
    __syncthreads();
    for (int it = 0; it < 19; ++it) {              // 25 rows * 192 outs
        const int q = t + 256 * it;
        if (q < 4800) {
            const int row = q / 192, oi = q - row * 192;
            const int o = (oi < 96) ? oi : oi - 96;
            const float* wr = W0s + o * 65 + ((oi < 96) ? 0 : 32);
            const float* xr = xs + row * 32;
            float a = (oi < 96) ? b0[o] : 0.0f;
#pragma unroll
            for (int k = 0; k < 32; ++k) a += wr[k] * xr[k];
            if (oi < 96) base0T[(r0 + row) * 96 + o] = a;
            else         Gp[(o >> 3) * 51200 + (r0 + row) * 8 + (o & 7)] = a;
        }
    }
    for (int i = t; i < 50; i += 256)
        xyt[(r0 + (i >> 1)) * 2 + (i & 1)] = xs[(i >> 1) * 32 + (i & 1)];
    for (int i = t; i < 800; i += 256)
        hin[(r0 + (i >> 5)) * 256 + 192 + (i & 31)] = xs[i];
}

// ---------------- edge kernel: ONE 512-thread block per (b,i) --------------
// R16 vs R15: the R15 result (VALU -24us, dur unchanged) proved the kernel
// is latency/barrier-bound at 2 blocks/CU. Buy a 3rd resident block:
// H2 shrinks to a 64-row buffer; L2/L3 run in two m-halves {m 0..3}, {4..6}
// with the L3 row-sums carried in registers across halves. LDS 60928->44800
// (3 blocks/CU, 6 waves/SIMD). Pad handling via acc-init only (H1/H2 pad
// rows are exact 0): L2b m=6 zero-init cols>=4; L3b m=2 zero-init g!=0.
__global__ __launch_bounds__(512, 4) void edge_kernel(
    const float* __restrict__ base0T, const float* __restrict__ Gp,
    const float* __restrict__ xyt, const float* __restrict__ wd0,
    const float* __restrict__ b1f, const float* __restrict__ b2f,
    const uint16_t* __restrict__ wb1, const uint16_t* __restrict__ wb2,
    float* __restrict__ hin)
{
    __shared__ __align__(16) uint16_t H1[112 * 104];   // 23296 B
    __shared__ __align__(16) uint16_t H2[64 * 168];    // 21504 B -> 44800 total

    const int bi = blockIdx.x, b = bi / 100;
    const int t = threadIdx.x, lane = t & 63, w = t >> 6;
    const int col = lane & 15, g = lane >> 4;

    // ---- build H1: t<448: row = t>>2 (0..111), c = t&3 -> c8 in {3c..3c+2}
    if (t < 448) {
        const int row = t >> 2, c = t & 3;
        if (row < 100) {
            const int jg = b * 100 + row;
            const float2 pj = *(const float2*)(xyt + 2 * jg);
            const float2 pi = *(const float2*)(xyt + 2 * bi);
            const float dx = pj.x - pi.x + 1e-12f, dy = pj.y - pi.y + 1e-12f;
            const float d = sqrtf(dx * dx + dy * dy);
#pragma unroll
            for (int i = 0; i < 3; ++i) {
                const int c8 = c * 3 + i, ow = c8 * 8;
                const float* gp = Gp + c8 * 51200 + jg * 8;
                const f32x4 g0 = *(const f32x4*)(gp);
                const f32x4 g1 = *(const f32x4*)(gp + 4);
                const f32x4 c0 = *(const f32x4*)(base0T + bi * 96 + ow);
                const f32x4 c1 = *(const f32x4*)(base0T + bi * 96 + ow + 4);
                const f32x4 w0v = *(const f32x4*)(wd0 + ow);
                const f32x4 w1v = *(const f32x4*)(wd0 + ow + 4);
                float v[8];
#pragma unroll
                for (int e = 0; e < 4; ++e) {
                    v[e]     = lrelu(g0[e] + c0[e] + w0v[e] * d);
                    v[4 + e] = lrelu(g1[e] + c1[e] + w1v[e] * d);
                }
                *(uint4*)(H1 + row * 104 + ow) =
                    (uint4){cvt2(v[0], v[1]), cvt2(v[2], v[3]),
                            cvt2(v[4], v[5]), cvt2(v[6], v[7])};
            }
        } else {
            const uint4 z = {0u, 0u, 0u, 0u};
#pragma unroll
            for (int i = 0; i < 3; ++i)
                *(uint4*)(H1 + row * 104 + (c * 3 + i) * 8) = z;
        }
    }
    __syncthreads();

    float s0 = 0.0f, s1 = 0.0f;
    const int nt0 = 2 * w, nt1 = 2 * w + 1;   // L2 uses w<5, L3 uses w<6

#pragma unroll
    for (int sub = 0; sub < 2; ++sub) {
        const int MT = sub ? 3 : 4;
        const int mb = sub ? 4 : 0;           // global m-tile base

        // ---- L2 sub (swapped): H2 rows = local m*16+col, j = (mb+m)*16+col
        if (w < 5) {
            f32x4 acc0[4], acc1[4];
            const f32x4 bb0 = *(const f32x4*)(b1f + nt0 * 16 + 4 * g);
            const f32x4 bb1 = *(const f32x4*)(b1f + nt1 * 16 + 4 * g);
            const f32x4 zz = {0.f, 0.f, 0.f, 0.f};
#pragma unroll
            for (int m = 0; m < 4; ++m) if (m < MT) {
                const bool pad = (sub == 1 && m == 2 && col >= 4);  // j=96+col
                acc0[m] = pad ? zz : bb0;
                acc1[m] = pad ? zz : bb1;
            }
            __builtin_amdgcn_s_setprio(1);
#pragma unroll
            for (int kt = 0; kt < 3; ++kt) {
                const bf16x8 wf0 = *(const bf16x8*)(wb1 + (nt0 * 16 + col) * 96 + kt * 32 + 8 * g);
                const bf16x8 wf1 = *(const bf16x8*)(wb1 + (nt1 * 16 + col) * 96 + kt * 32 + 8 * g);
#pragma unroll
                for (int m = 0; m < 4; ++m) if (m < MT) {
                    const bf16x8 hf = *(const bf16x8*)(H1 + ((mb + m) * 16 + col) * 104 + kt * 32 + 8 * g);
                    acc0[m] = __builtin_amdgcn_mfma_f32_16x16x32_bf16(wf0, hf, acc0[m], 0, 0, 0);
                    acc1[m] = __builtin_amdgcn_mfma_f32_16x16x32_bf16(wf1, hf, acc1[m], 0, 0, 0);
                }
            }
            __builtin_amdgcn_s_setprio(0);
#pragma unroll
            for (int m = 0; m < 4; ++m) if (m < MT) {
                {
                    const uint32_t p01 = cvt2(lrelu(acc0[m][0]), lrelu(acc0[m][1]));
                    const uint32_t p23 = cvt2(lrelu(acc0[m][2]), lrelu(acc0[m][3]));
                    *(uint2*)(H2 + (m * 16 + col) * 168 + nt0 * 16 + 4 * g) = (uint2){p01, p23};
                }
                {
                    const uint32_t p01 = cvt2(lrelu(acc1[m][0]), lrelu(acc1[m][1]));
                    const uint32_t p23 = cvt2(lrelu(acc1[m][2]), lrelu(acc1[m][3]));
                    *(uint2*)(H2 + (m * 16 + col) * 168 + nt1 * 16 + 4 * g) = (uint2){p01, p23};
                }
            }
        }
        __syncthreads();

        // ---- L3 sub: partial row-sums over this m-half (rows exact-0 pad)
        if (w < 6) {
            f32x4 acc0[4], acc1[4];
            const float bv0 = b2f[nt0 * 16 + col];
            const float bv1 = b2f[nt1 * 16 + col];
#pragma unroll
            for (int m = 0; m < 4; ++m) if (m < MT) {
                // sub1 m=2: global rows 96+4g+r -> pad iff g!=0
                const bool pad = (sub == 1 && m == 2 && g != 0);
                const float a0 = pad ? 0.0f : bv0;
                const float a1 = pad ? 0.0f : bv1;
                acc0[m] = (f32x4){a0, a0, a0, a0};
                acc1[m] = (f32x4){a1, a1, a1, a1};
            }
            __builtin_amdgcn_s_setprio(1);
#pragma unroll
            for (int kt = 0; kt < 5; ++kt) {
                const bf16x8 bf0 = *(const bf16x8*)(wb2 + (nt0 * 16 + col) * 160 + kt * 32 + 8 * g);
                const bf16x8 bf1 = *(const bf16x8*)(wb2 + (nt1 * 16 + col) * 160 + kt * 32 + 8 * g);
#pragma unroll
                for (int m = 0; m < 4; ++m) if (m < MT) {
                    const bf16x8 af = *(const bf16x8*)(H2 + (m * 16 + col) * 168 + kt * 32 + 8 * g);
                    acc0[m] = __builtin_amdgcn_mfma_f32_16x16x32_bf16(af, bf0, acc0[m], 0, 0, 0);
                    acc1[m] = __builtin_amdgcn_mfma_f32_16x16x32_bf16(af, bf1, acc1[m], 0, 0, 0);
                }
            }
            __builtin_amdgcn_s_setprio(0);
#pragma unroll
            for (int m = 0; m < 4; ++m) if (m < MT) {
#pragma unroll
                for (int r = 0; r < 4; ++r) {
                    s0 += lrelu(acc0[m][r]);      // pad rows contribute 0
                    s1 += lrelu(acc1[m][r]);
                }
            }
        }
        if (sub == 0) __syncthreads();
    }

    if (w < 6) {
        s0 += __shfl_xor(s0, 16);
        s0 += __shfl_xor(s0, 32);
        s1 += __shfl_xor(s1, 16);
        s1 += __shfl_xor(s1, 32);
        if (lane < 16) {
            hin[bi * 256 + nt0 * 16 + col] = s0;
            hin[bi * 256 + nt1 * 16 + col] = s1;
        }
    }
}

// ---------------- fused node MLP: 16 rows per block, 400 blocks ------------
__global__ __launch_bounds__(256) void node_kernel(
    const float* __restrict__ hin,
    const uint16_t* __restrict__ wfn0, const float* __restrict__ fb0,
    const uint16_t* __restrict__ wfn1, const float* __restrict__ fb1,
    const float* __restrict__ fw2, const float* __restrict__ fb2,
    float* __restrict__ out)
{
    __shared__ __align__(16) uint16_t RA[16 * 264];
    __shared__ __align__(16) uint16_t RH[16 * 264];
    const int t = threadIdx.x, lane = t & 63, wave = t >> 6;
    const int col = lane & 15, g = lane >> 4;
    const int r0 = blockIdx.x * 16;

    for (int r = wave; r < 16; r += 4) {
        const float* src = hin + (r0 + r) * 256;
        for (int c = lane; c < 224; c += 64)
            RA[r * 232 + c] = f2b(src[c]);
    }
    __syncthreads();
    {   // L0: 224 -> 256
        f32x4 acc[4];
#pragma unroll
        for (int s = 0; s < 4; ++s) {
            const float bv = fb0[(wave + 4 * s) * 16 + col];
            acc[s] = (f32x4){bv, bv, bv, bv};
        }
#pragma unroll
        for (int kt = 0; kt < 7; ++kt) {
            const bf16x8 afr = *(const bf16x8*)(RA + col * 232 + kt * 32 + 8 * g);
#pragma unroll
            for (int s = 0; s < 4; ++s) {
                const bf16x8 bfr = *(const bf16x8*)(
                    wfn0 + ((wave + 4 * s) * 16 + col) * 224 + kt * 32 + 8 * g);
                acc[s] = __builtin_amdgcn_mfma_f32_16x16x32_bf16(afr, bfr, acc[s], 0, 0, 0);
            }
        }
#pragma unroll
        for (int s = 0; s < 4; ++s)
#pragma unroll
            for (int r = 0; r < 4; ++r)
                RH[(4 * g + r) * 264 + (wave + 4 * s) * 16 + col] = f2b(lrelu(acc[s][r]));
    }
    __syncthreads();
    {   // L1: 256 -> 256
        f32x4 acc[4];
#pragma unroll
        for (int s = 0; s < 4; ++s) {
            const float bv = fb1[(wave + 4 * s) * 16 + col];
            acc[s] = (f32x4){bv, bv, bv, bv};
        }
#pragma unroll
        for (int kt = 0; kt < 8; ++kt) {
            const bf16x8 afr = *(const bf16x8*)(RH + col * 264 + kt * 32 + 8 * g);
#pragma unroll
            for (int s = 0; s < 4; ++s) {
                const bf16x8 bfr = *(const bf16x8*)(
                    wfn1 + ((wave + 4 * s) * 16 + col) * 256 + kt * 32 + 8 * g);
                acc[s] = __builtin_amdgcn_mfma_f32_16x16x32_bf16(afr, bfr, acc[s], 0, 0, 0);
            }
        }
        __syncthreads();
#pragma unroll
        for (int s = 0; s < 4; ++s)
#pragma unroll
            for (int r = 0; r < 4; ++r)
                RA[(4 * g + r) * 264 + (wave + 4 * s) * 16 + col] = f2b(lrelu(acc[s][r]));
    }
    __syncthreads();
    // L2 final: 3 outputs fp32 + tanh
    const int row = t >> 4, u = t & 15;
    float h = 0.0f;
    if (u < 12) {
        const int o = u >> 2, ks = u & 3;
        const float* wv = fw2 + o * 256 + ks * 64;
        const uint16_t* hr = RA + row * 264 + ks * 64;
        float a = 0.0f;
#pragma unroll 8
        for (int k = 0; k < 64; k += 4) {
            const ushort4 hv = *(const ushort4*)(hr + k);
            union { uint32_t u; float f; } c0, c1, c2, c3;
            c0.u = (uint32_t)hv.x << 16; c1.u = (uint32_t)hv.y << 16;
            c2.u = (uint32_t)hv.z << 16; c3.u = (uint32_t)hv.w << 16;
            a += wv[k] * c0.f + wv[k + 1] * c1.f + wv[k + 2] * c2.f + wv[k + 3] * c3.f;
        }
        h = a;
    }
    h += __shfl_xor(h, 1);
    h += __shfl_xor(h, 2);
    if (u < 12 && (u & 3) == 0)
        out[(r0 + row) * 3 + (u >> 2)] = tanhf(h + fb2[u >> 2]);
}

extern "C" void kernel_launch(void* const* d_in, const int* in_sizes, int n_in,
                              void* d_out, int out_size, void* d_ws, size_t ws_size,
                              hipStream_t stream) {
    (void)in_sizes; (void)n_in; (void)out_size; (void)ws_size;
    const float* x     = (const float*)d_in[0];
    const float* fe_w0 = (const float*)d_in[1];
    const float* fe_b0 = (const float*)d_in[2];
    const float* fe_w1 = (const float*)d_in[3];
    const float* fe_b1 = (const float*)d_in[4];
    const float* fe_w2 = (const float*)d_in[5];
    const float* fe_b2 = (const float*)d_in[6];
    const float* fn_w0 = (const float*)d_in[7];
    const float* fn_b0 = (const float*)d_in[8];
    const float* fn_w1 = (const float*)d_in[9];
    const float* fn_b1 = (const float*)d_in[10];
    const float* fn_w2 = (const float*)d_in[11];
    const float* fn_b2 = (const float*)d_in[12];
    float* out = (float*)d_out;

    float* buf0   = (float*)d_ws;                     // hin [6400][256] f32
    float* base0T = buf0 + (size_t)6400 * 256;        // [6400][96]
    float* Gp     = base0T + 6400 * 96;               // [12][6400][8]
    float* xyt    = Gp + 6400 * 96;                   // [6400][2]
    float* wd0    = xyt + 12800;                      // 96 (pad 128)
    uint16_t* wb1  = (uint16_t*)(wd0 + 128);          // 160*96
    uint16_t* wb2  = wb1 + 160 * 96;                  // 192*160
    uint16_t* wfn0 = wb2 + 192 * 160;                 // 256*224
    uint16_t* wfn1 = wfn0 + 256 * 224;                // 256*256

    precompute<<<284, 256, 0, stream>>>(x, fe_w0, fe_b0, fe_w1, fe_w2,
                                        fn_w0, fn_w1,
                                        base0T, Gp, xyt, wd0,
                                        wb1, wb2, wfn0, wfn1, buf0);
    edge_kernel<<<6400, 512, 0, stream>>>(base0T, Gp, xyt, wd0,
                                          fe_b1, fe_b2, wb1, wb2, buf0);
    node_kernel<<<400, 256, 0, stream>>>(buf0, wfn0, fn_b0, wfn1, fn_b1,
                                         fn_w2, fn_b2, out);
}

// Round 17
// 148.801 us; speedup vs baseline: 1.1056x; 1.1056x over previous
//
#include <hip/hip_runtime.h>
#include <math.h>

#define ALPHA 0.2f

typedef __attribute__((ext_vector_type(8))) short bf16x8;
typedef __attribute__((ext_vector_type(4))) float f32x4;

static __device__ __forceinline__ float lrelu(float v) {
    return fmaxf(v, ALPHA * v);
}
// fp32 -> bf16 RTNE (software; low-volume paths only)
static __device__ __forceinline__ uint16_t f2b(float f) {
    union { float f; uint32_t u; } c; c.f = f;
    const uint32_t u = c.u + 0x7FFFu + ((c.u >> 16) & 1u);
    return (uint16_t)(u >> 16);
}
// HW packed cvt: low16 = bf16(lo), high16 = bf16(hi), RTNE
static __device__ __forceinline__ uint32_t cvt2(float lo, float hi) {
    uint32_t r;
    asm("v_cvt_pk_bf16_f32 %0, %1, %2" : "=v"(r) : "v"(lo), "v"(hi));
    return r;
}

// ---------------- precompute (hin tail now bf16) ---------------------------
__global__ __launch_bounds__(256) void precompute(
    const float* __restrict__ x, const float* __restrict__ w0,
    const float* __restrict__ b0, const float* __restrict__ w1,
    const float* __restrict__ w2, const float* __restrict__ f0,
    const float* __restrict__ f1,
    float* __restrict__ base0T, float* __restrict__ Gp,
    float* __restrict__ xyt, float* __restrict__ wd0,
    uint16_t* __restrict__ wb1, uint16_t* __restrict__ wb2,
    uint16_t* __restrict__ wfn0, uint16_t* __restrict__ wfn1,
    uint16_t* __restrict__ hinb)
{
    const int blk = blockIdx.x, t = threadIdx.x;
    if (blk >= 256) {
        const int t0 = (blk - 256) * 256 + t;  // 0..7167
        for (int i = t0; i < 160 * 96;  i += 7168) wb1[i]  = f2b(w1[i]);
        for (int i = t0; i < 192 * 160; i += 7168) wb2[i]  = f2b(w2[i]);
        for (int i = t0; i < 256 * 224; i += 7168) wfn0[i] = f2b(f0[i]);
        for (int i = t0; i < 256 * 256; i += 7168) wfn1[i] = f2b(f1[i]);
        if (t0 < 96) wd0[t0] = w0[t0 * 65 + 64];
        return;
    }
    __shared__ float W0s[96 * 65];
    __shared__ float xs[25 * 32];
    const int r0 = blk * 25;
    for (int i = t; i < 96 * 65; i += 256) W0s[i] = w0[i];
    for (int i = t; i < 800; i += 256) xs[i] = x[r0 * 32 + i];
    __syncthreads();
    for (int it = 0; it < 19; ++it) {              // 25 rows * 192 outs
        const int q = t + 256 * it;
        if (q < 4800) {
            const int row = q / 192, oi = q - row * 192;
            const int o = (oi < 96) ? oi : oi - 96;
            const float* wr = W0s + o * 65 + ((oi < 96) ? 0 : 32);
            const float* xr = xs + row * 32;
            float a = (oi < 96) ? b0[o] : 0.0f;
#pragma unroll
            for (int k = 0; k < 32; ++k) a += wr[k] * xr[k];
            if (oi < 96) base0T[(r0 + row) * 96 + o] = a;
            else         Gp[(o >> 3) * 51200 + (r0 + row) * 8 + (o & 7)] = a;
        }
    }
    for (int i = t; i < 50; i += 256)
        xyt[(r0 + (i >> 1)) * 2 + (i & 1)] = xs[(i >> 1) * 32 + (i & 1)];
    for (int i = t; i < 800; i += 256)
        hinb[(r0 + (i >> 5)) * 256 + 192 + (i & 31)] = f2b(xs[i]);
}

// ---------------- edge kernel: R15 verbatim (best: 132.6us), bf16 out ------
// R15/R14's 2-barrier, 2-block/CU config is the measured local optimum of
// this fused structure (R11 VALU-diet: flat; R16 3-blocks+2-barriers: -10%;
// R12/R13 topology variants: worse). Only change here: j-sums are written
// as bf16 (f2b = same RTNE the node kernel applied) -> node staging becomes
// pure uint4 copies and hin round-trip traffic halves.
__global__ __launch_bounds__(512, 4) void edge_kernel(
    const float* __restrict__ base0T, const float* __restrict__ Gp,
    const float* __restrict__ xyt, const float* __restrict__ wd0,
    const float* __restrict__ b1f, const float* __restrict__ b2f,
    const uint16_t* __restrict__ wb1, const uint16_t* __restrict__ wb2,
    uint16_t* __restrict__ hinb)
{
    __shared__ __align__(16) uint16_t H1[112 * 104];
    __shared__ __align__(16) uint16_t H2[112 * 168];

    const int bi = blockIdx.x, b = bi / 100;
    const int t = threadIdx.x, lane = t & 63, w = t >> 6;
    const int col = lane & 15, g = lane >> 4;

    // ---- build H1: t<448: row = t>>2 (0..111), c = t&3 -> c8 in {3c..3c+2}
    if (t < 448) {
        const int row = t >> 2, c = t & 3;
        if (row < 100) {
            const int jg = b * 100 + row;
            const float2 pj = *(const float2*)(xyt + 2 * jg);
            const float2 pi = *(const float2*)(xyt + 2 * bi);
            const float dx = pj.x - pi.x + 1e-12f, dy = pj.y - pi.y + 1e-12f;
            const float d = sqrtf(dx * dx + dy * dy);
#pragma unroll
            for (int i = 0; i < 3; ++i) {
                const int c8 = c * 3 + i, ow = c8 * 8;
                const float* gp = Gp + c8 * 51200 + jg * 8;
                const f32x4 g0 = *(const f32x4*)(gp);
                const f32x4 g1 = *(const f32x4*)(gp + 4);
                const f32x4 c0 = *(const f32x4*)(base0T + bi * 96 + ow);
                const f32x4 c1 = *(const f32x4*)(base0T + bi * 96 + ow + 4);
                const f32x4 w0v = *(const f32x4*)(wd0 + ow);
                const f32x4 w1v = *(const f32x4*)(wd0 + ow + 4);
                float v[8];
#pragma unroll
                for (int e = 0; e < 4; ++e) {
                    v[e]     = lrelu(g0[e] + c0[e] + w0v[e] * d);
                    v[4 + e] = lrelu(g1[e] + c1[e] + w1v[e] * d);
                }
                *(uint4*)(H1 + row * 104 + ow) =
                    (uint4){cvt2(v[0], v[1]), cvt2(v[2], v[3]),
                            cvt2(v[4], v[5]), cvt2(v[6], v[7])};
            }
        } else {
            const uint4 z = {0u, 0u, 0u, 0u};
#pragma unroll
            for (int i = 0; i < 3; ++i)
                *(uint4*)(H1 + row * 104 + (c * 3 + i) * 8) = z;
        }
    }
    __syncthreads();

    // ---- L2 (swapped): D[n][j]; waves 0..4 own nt = {2w, 2w+1} ----
    if (w < 5) {
        const int nt0 = 2 * w, nt1 = 2 * w + 1;
        f32x4 acc0[7], acc1[7];
        const f32x4 bb0 = *(const f32x4*)(b1f + nt0 * 16 + 4 * g);
        const f32x4 bb1 = *(const f32x4*)(b1f + nt1 * 16 + 4 * g);
#pragma unroll
        for (int m = 0; m < 7; ++m) { acc0[m] = bb0; acc1[m] = bb1; }
        __builtin_amdgcn_s_setprio(1);
#pragma unroll
        for (int kt = 0; kt < 3; ++kt) {
            const bf16x8 wf0 = *(const bf16x8*)(wb1 + (nt0 * 16 + col) * 96 + kt * 32 + 8 * g);
            const bf16x8 wf1 = *(const bf16x8*)(wb1 + (nt1 * 16 + col) * 96 + kt * 32 + 8 * g);
#pragma unroll
            for (int m = 0; m < 7; ++m) {
                const bf16x8 hf = *(const bf16x8*)(H1 + (m * 16 + col) * 104 + kt * 32 + 8 * g);
                acc0[m] = __builtin_amdgcn_mfma_f32_16x16x32_bf16(wf0, hf, acc0[m], 0, 0, 0);
                acc1[m] = __builtin_amdgcn_mfma_f32_16x16x32_bf16(wf1, hf, acc1[m], 0, 0, 0);
            }
        }
        __builtin_amdgcn_s_setprio(0);
#pragma unroll
        for (int m = 0; m < 7; ++m) {
            {
                const uint32_t p01 = cvt2(lrelu(acc0[m][0]), lrelu(acc0[m][1]));
                const uint32_t p23 = cvt2(lrelu(acc0[m][2]), lrelu(acc0[m][3]));
                *(uint2*)(H2 + (m * 16 + col) * 168 + nt0 * 16 + 4 * g) = (uint2){p01, p23};
            }
            {
                const uint32_t p01 = cvt2(lrelu(acc1[m][0]), lrelu(acc1[m][1]));
                const uint32_t p23 = cvt2(lrelu(acc1[m][2]), lrelu(acc1[m][3]));
                *(uint2*)(H2 + (m * 16 + col) * 168 + nt1 * 16 + 4 * g) = (uint2){p01, p23};
            }
        }
    }
    __syncthreads();

    // ---- L3: masked row-sum; waves 0..5 own nt = {2w, 2w+1} ----
    if (w < 6) {
        const int nt0 = 2 * w, nt1 = 2 * w + 1;
        f32x4 acc0[7], acc1[7];
        const float bv0 = b2f[nt0 * 16 + col];
        const float bv1 = b2f[nt1 * 16 + col];
#pragma unroll
        for (int m = 0; m < 7; ++m) {
            acc0[m] = (f32x4){bv0, bv0, bv0, bv0};
            acc1[m] = (f32x4){bv1, bv1, bv1, bv1};
        }
        __builtin_amdgcn_s_setprio(1);
#pragma unroll
        for (int kt = 0; kt < 5; ++kt) {
            const bf16x8 bf0 = *(const bf16x8*)(wb2 + (nt0 * 16 + col) * 160 + kt * 32 + 8 * g);
            const bf16x8 bf1 = *(const bf16x8*)(wb2 + (nt1 * 16 + col) * 160 + kt * 32 + 8 * g);
#pragma unroll
            for (int m = 0; m < 7; ++m) {
                const bf16x8 af = *(const bf16x8*)(H2 + (m * 16 + col) * 168 + kt * 32 + 8 * g);
                acc0[m] = __builtin_amdgcn_mfma_f32_16x16x32_bf16(af, bf0, acc0[m], 0, 0, 0);
                acc1[m] = __builtin_amdgcn_mfma_f32_16x16x32_bf16(af, bf1, acc1[m], 0, 0, 0);
            }
        }
        __builtin_amdgcn_s_setprio(0);
        float s0 = 0.0f, s1 = 0.0f;
#pragma unroll
        for (int m = 0; m < 7; ++m) {
            const int rowbase = m * 16 + 4 * g;
#pragma unroll
            for (int r = 0; r < 4; ++r) {
                const bool ok = (m < 6) || (rowbase + r < 100);
                if (ok) {
                    s0 += lrelu(acc0[m][r]);
                    s1 += lrelu(acc1[m][r]);
                }
            }
        }
        s0 += __shfl_xor(s0, 16);
        s0 += __shfl_xor(s0, 32);
        s1 += __shfl_xor(s1, 16);
        s1 += __shfl_xor(s1, 32);
        if (lane < 16) {
            hinb[bi * 256 + nt0 * 16 + col] = f2b(s0);
            hinb[bi * 256 + nt1 * 16 + col] = f2b(s1);
        }
    }
}

// ---------------- fused node MLP: 16 rows per block, 400 blocks ------------
// Input rows are already bf16 -> staging is pure uint4 copies (no f2b).
__global__ __launch_bounds__(256) void node_kernel(
    const uint16_t* __restrict__ hinb,
    const uint16_t* __restrict__ wfn0, const float* __restrict__ fb0,
    const uint16_t* __restrict__ wfn1, const float* __restrict__ fb1,
    const float* __restrict__ fw2, const float* __restrict__ fb2,
    float* __restrict__ out)
{
    __shared__ __align__(16) uint16_t RA[16 * 264];
    __shared__ __align__(16) uint16_t RH[16 * 264];
    const int t = threadIdx.x, lane = t & 63, wave = t >> 6;
    const int col = lane & 15, g = lane >> 4;
    const int r0 = blockIdx.x * 16;

    // 16 rows x 28 uint4 (224 bf16) -> RA stride 232
    for (int idx = t; idx < 512; idx += 256) {
        const int r = idx >> 5, c = idx & 31;
        if (c < 28) {
            const uint4 v = *(const uint4*)(hinb + (r0 + r) * 256 + c * 8);
            *(uint4*)(RA + r * 232 + c * 8) = v;
        }
    }
    __syncthreads();
    {   // L0: 224 -> 256
        f32x4 acc[4];
#pragma unroll
        for (int s = 0; s < 4; ++s) {
            const float bv = fb0[(wave + 4 * s) * 16 + col];
            acc[s] = (f32x4){bv, bv, bv, bv};
        }
#pragma unroll
        for (int kt = 0; kt < 7; ++kt) {
            const bf16x8 afr = *(const bf16x8*)(RA + col * 232 + kt * 32 + 8 * g);
#pragma unroll
            for (int s = 0; s < 4; ++s) {
                const bf16x8 bfr = *(const bf16x8*)(
                    wfn0 + ((wave + 4 * s) * 16 + col) * 224 + kt * 32 + 8 * g);
                acc[s] = __builtin_amdgcn_mfma_f32_16x16x32_bf16(afr, bfr, acc[s], 0, 0, 0);
            }
        }
#pragma unroll
        for (int s = 0; s < 4; ++s)
#pragma unroll
            for (int r = 0; r < 4; ++r)
                RH[(4 * g + r) * 264 + (wave + 4 * s) * 16 + col] = f2b(lrelu(acc[s][r]));
    }
    __syncthreads();
    {   // L1: 256 -> 256
        f32x4 acc[4];
#pragma unroll
        for (int s = 0; s < 4; ++s) {
            const float bv = fb1[(wave + 4 * s) * 16 + col];
            acc[s] = (f32x4){bv, bv, bv, bv};
        }
#pragma unroll
        for (int kt = 0; kt < 8; ++kt) {
            const bf16x8 afr = *(const bf16x8*)(RH + col * 264 + kt * 32 + 8 * g);
#pragma unroll
            for (int s = 0; s < 4; ++s) {
                const bf16x8 bfr = *(const bf16x8*)(
                    wfn1 + ((wave + 4 * s) * 16 + col) * 256 + kt * 32 + 8 * g);
                acc[s] = __builtin_amdgcn_mfma_f32_16x16x32_bf16(afr, bfr, acc[s], 0, 0, 0);
            }
        }
        __syncthreads();
#pragma unroll
        for (int s = 0; s < 4; ++s)
#pragma unroll
            for (int r = 0; r < 4; ++r)
                RA[(4 * g + r) * 264 + (wave + 4 * s) * 16 + col] = f2b(lrelu(acc[s][r]));
    }
    __syncthreads();
    // L2 final: 3 outputs fp32 + tanh
    const int row = t >> 4, u = t & 15;
    float h = 0.0f;
    if (u < 12) {
        const int o = u >> 2, ks = u & 3;
        const float* wv = fw2 + o * 256 + ks * 64;
        const uint16_t* hr = RA + row * 264 + ks * 64;
        float a = 0.0f;
#pragma unroll 8
        for (int k = 0; k < 64; k += 4) {
            const ushort4 hv = *(const ushort4*)(hr + k);
            union { uint32_t u; float f; } c0, c1, c2, c3;
            c0.u = (uint32_t)hv.x << 16; c1.u = (uint32_t)hv.y << 16;
            c2.u = (uint32_t)hv.z << 16; c3.u = (uint32_t)hv.w << 16;
            a += wv[k] * c0.f + wv[k + 1] * c1.f + wv[k + 2] * c2.f + wv[k + 3] * c3.f;
        }
        h = a;
    }
    h += __shfl_xor(h, 1);
    h += __shfl_xor(h, 2);
    if (u < 12 && (u & 3) == 0)
        out[(r0 + row) * 3 + (u >> 2)] = tanhf(h + fb2[u >> 2]);
}

extern "C" void kernel_launch(void* const* d_in, const int* in_sizes, int n_in,
                              void* d_out, int out_size, void* d_ws, size_t ws_size,
                              hipStream_t stream) {
    (void)in_sizes; (void)n_in; (void)out_size; (void)ws_size;
    const float* x     = (const float*)d_in[0];
    const float* fe_w0 = (const float*)d_in[1];
    const float* fe_b0 = (const float*)d_in[2];
    const float* fe_w1 = (const float*)d_in[3];
    const float* fe_b1 = (const float*)d_in[4];
    const float* fe_w2 = (const float*)d_in[5];
    const float* fe_b2 = (const float*)d_in[6];
    const float* fn_w0 = (const float*)d_in[7];
    const float* fn_b0 = (const float*)d_in[8];
    const float* fn_w1 = (const float*)d_in[9];
    const float* fn_b1 = (const float*)d_in[10];
    const float* fn_w2 = (const float*)d_in[11];
    const float* fn_b2 = (const float*)d_in[12];
    float* out = (float*)d_out;

    uint16_t* hinb = (uint16_t*)d_ws;                 // [6400][256] bf16
    float* base0T  = (float*)(hinb + 6400 * 256);     // [6400][96]
    float* Gp      = base0T + 6400 * 96;              // [12][6400][8]
    float* xyt     = Gp + 6400 * 96;                  // [6400][2]
    float* wd0     = xyt + 12800;                     // 96 (pad 128)
    uint16_t* wb1  = (uint16_t*)(wd0 + 128);          // 160*96
    uint16_t* wb2  = wb1 + 160 * 96;                  // 192*160
    uint16_t* wfn0 = wb2 + 192 * 160;                 // 256*224
    uint16_t* wfn1 = wfn0 + 256 * 224;                // 256*256

    precompute<<<284, 256, 0, stream>>>(x, fe_w0, fe_b0, fe_w1, fe_w2,
                                        fn_w0, fn_w1,
                                        base0T, Gp, xyt, wd0,
                                        wb1, wb2, wfn0, wfn1, hinb);
    edge_kernel<<<6400, 512, 0, stream>>>(base0T, Gp, xyt, wd0,
                                          fe_b1, fe_b2, wb1, wb2, hinb);
    node_kernel<<<400, 256, 0, stream>>>(hinb, wfn0, fn_b0, wfn1, fn_b1,
                                         fn_w2, fn_b2, out);
}